// Round 17
// baseline (72.566 us; speedup 1.0000x reference)
//
#include <hip/hip_runtime.h>

using u16 = unsigned short;
using u32 = unsigned int;
using u64 = unsigned long long;

#define ALPHA 0.2f
#define LOG2E 1.4426950408889634f

typedef __bf16 bf16x8 __attribute__((ext_vector_type(8)));
typedef float f32x4 __attribute__((ext_vector_type(4)));
typedef float f32x16 __attribute__((ext_vector_type(16)));

__device__ __forceinline__ u16 f2bf(float f) {
  u32 u = __builtin_bit_cast(u32, f);
  u += 0x7FFFu + ((u >> 16) & 1u);   // RTNE
  return (u16)(u >> 16);
}
__device__ __forceinline__ float bf2f(u16 h) {
  u32 u = ((u32)h) << 16;
  return __builtin_bit_cast(float, u);
}
__device__ __forceinline__ void gload_lds16(const void* g, void* l) {
  __builtin_amdgcn_global_load_lds((__attribute__((address_space(1))) void*)g,
                                   (__attribute__((address_space(3))) void*)l,
                                   16, 0, 0);
}

// ---------- cast+transpose W: wbt[n][k] = bf16(W[k][n]) ----------
__global__ __launch_bounds__(256) void k_cast_wT(const float* __restrict__ W, u16* __restrict__ wbt) {
  int idx = blockIdx.x * 256 + threadIdx.x;
  int k = idx >> 9, n = idx & 511;
  wbt[n * 512 + k] = f2bf(W[idx]);
}

// ---------- gemm1: h = x@W (M=16384,K=512,N=512). 128x128 tile, 4 waves.
// Triple-buffered, counted vmcnt, XCD-swizzled. Epilogue: hbf + score partials.
__global__ __launch_bounds__(256, 2) void k_gemm1(const float* __restrict__ x, const u16* __restrict__ wbt,
                                                  const float* __restrict__ a,
                                                  u16* __restrict__ hbf,
                                                  float* __restrict__ s1p, float* __restrict__ s2p) {
  __shared__ __attribute__((aligned(16))) char lds[73728];
  __shared__ __attribute__((aligned(16))) float a_l[256];

  const int t = threadIdx.x;
  const int lane = t & 63;
  const int w = t >> 6;
  const int l31 = lane & 31, lhi = lane >> 5;
  const int rb = w >> 1, cg = w & 1;
  const int g = blockIdx.x;
  const int cb = (g >> 3) & 3;
  const int tile_m = (g & 7) | ((g >> 5) << 3);
  const int row0 = tile_m * 128;
  const int col0 = cb * 128;

  a_l[t] = (t < 128) ? a[col0 + t] : a[512 + col0 + (t - 128)];

  f32x16 acc[2][2];
#pragma unroll
  for (int i = 0; i < 2; ++i)
#pragma unroll
    for (int j = 0; j < 2; ++j)
#pragma unroll
      for (int r = 0; r < 16; ++r) acc[i][j][r] = 0.f;

#define STAGE_G1(kt, Ab, Bb)                                                              \
  {                                                                                       \
    const int k0_ = (kt) * 32;                                                            \
    _Pragma("unroll")                                                                     \
    for (int i = 0; i < 4; ++i) {                                                         \
      int G = i * 256 + t;                                                                \
      int row = G >> 3, ks = G & 7;                                                       \
      gload_lds16(x + (size_t)(row0 + row) * 512 + k0_ + ((ks ^ (row & 7)) * 4),          \
                  (Ab) + (size_t)(i * 256 + w * 64) * 16);                                \
    }                                                                                     \
    _Pragma("unroll")                                                                     \
    for (int i = 0; i < 2; ++i) {                                                         \
      int G = i * 256 + t;                                                                \
      int col = G >> 2, ks = G & 3;                                                       \
      gload_lds16(wbt + (size_t)(col0 + col) * 512 + k0_ + ((ks ^ ((col >> 1) & 3)) * 8), \
                  (Bb) + (size_t)(i * 256 + w * 64) * 16);                                \
    }                                                                                     \
  }

#define COMPUTE_G1(Ab, Bb)                                                                         \
  {                                                                                                \
    _Pragma("unroll")                                                                              \
    for (int ks = 0; ks < 2; ++ks) {                                                               \
      bf16x8 af[2];                                                                                \
      _Pragma("unroll")                                                                            \
      for (int sub = 0; sub < 2; ++sub) {                                                          \
        const int arow = rb * 64 + sub * 32 + l31;                                                 \
        const int kg = ks * 4 + lhi * 2;                                                           \
        f32x4 fa0 = *reinterpret_cast<const f32x4*>((Ab) + (size_t)(arow * 8 + (kg ^ (arow & 7))) * 16); \
        f32x4 fa1 = *reinterpret_cast<const f32x4*>((Ab) + (size_t)(arow * 8 + ((kg + 1) ^ (arow & 7))) * 16); \
        _Pragma("unroll")                                                                          \
        for (int jj = 0; jj < 4; ++jj) {                                                           \
          af[sub][jj] = (__bf16)fa0[jj];                                                           \
          af[sub][jj + 4] = (__bf16)fa1[jj];                                                       \
        }                                                                                          \
      }                                                                                            \
      bf16x8 bfr[2];                                                                               \
      _Pragma("unroll")                                                                            \
      for (int bt = 0; bt < 2; ++bt) {                                                             \
        const int bcol = cg * 64 + bt * 32 + l31;                                                  \
        const int kslot = (ks * 2 + lhi) ^ ((bcol >> 1) & 3);                                      \
        bfr[bt] = *reinterpret_cast<const bf16x8*>((Bb) + (size_t)(bcol * 4 + kslot) * 16);        \
      }                                                                                            \
      _Pragma("unroll")                                                                            \
      for (int sub = 0; sub < 2; ++sub)                                                            \
        _Pragma("unroll")                                                                          \
        for (int bt = 0; bt < 2; ++bt)                                                             \
          acc[sub][bt] = __builtin_amdgcn_mfma_f32_32x32x16_bf16(af[sub], bfr[bt], acc[sub][bt], 0, 0, 0); \
    }                                                                                              \
  }

  char* Ac = lds;             char* Bc = lds + 49152;
  char* An = lds + 16384;     char* Bn = lds + 57344;
  char* As = lds + 32768;     char* Bs = lds + 65536;

  STAGE_G1(0, Ac, Bc);
  STAGE_G1(1, An, Bn);
  __builtin_amdgcn_sched_barrier(0);
  asm volatile("s_waitcnt vmcnt(6) lgkmcnt(0)" ::: "memory");
  __builtin_amdgcn_s_barrier();
  __builtin_amdgcn_sched_barrier(0);

#pragma unroll 1
  for (int kt = 0; kt < 14; ++kt) {
    STAGE_G1(kt + 2, As, Bs);
    COMPUTE_G1(Ac, Bc);
    __builtin_amdgcn_sched_barrier(0);
    asm volatile("s_waitcnt vmcnt(6)" ::: "memory");
    __builtin_amdgcn_s_barrier();
    __builtin_amdgcn_sched_barrier(0);
    char* ta = Ac; Ac = An; An = As; As = ta;
    char* tb = Bc; Bc = Bn; Bn = Bs; Bs = tb;
  }
  COMPUTE_G1(Ac, Bc);
  __builtin_amdgcn_sched_barrier(0);
  asm volatile("s_waitcnt vmcnt(0)" ::: "memory");
  __builtin_amdgcn_s_barrier();
  __builtin_amdgcn_sched_barrier(0);
  COMPUTE_G1(An, Bn);
#undef STAGE_G1
#undef COMPUTE_G1

  __syncthreads();

  u16* lT = (u16*)lds;
#pragma unroll
  for (int sub = 0; sub < 2; ++sub)
#pragma unroll
    for (int bt = 0; bt < 2; ++bt) {
      const int col = cg * 64 + bt * 32 + l31;
#pragma unroll
      for (int r = 0; r < 16; ++r) {
        int row = rb * 64 + sub * 32 + (r & 3) + 8 * (r >> 2) + 4 * lhi;
        lT[row * 136 + col] = f2bf(acc[sub][bt][r]);
      }
    }
  __syncthreads();

#pragma unroll
  for (int i = 0; i < 8; ++i) {
    int G = i * 256 + t;
    int row = G >> 4, gg = G & 15;
    uint4 v = *reinterpret_cast<const uint4*>(&lT[row * 136 + gg * 8]);
    *reinterpret_cast<uint4*>(&hbf[(size_t)(row0 + row) * 512 + col0 + gg * 8]) = v;
  }
  {
    const int r2 = t >> 1, half = t & 1;
    float d1 = 0.f, d2 = 0.f;
#pragma unroll
    for (int i = 0; i < 8; ++i) {
      uint4 v = *reinterpret_cast<const uint4*>(&lT[r2 * 136 + half * 64 + i * 8]);
      u32 wds[4] = {v.x, v.y, v.z, v.w};
#pragma unroll
      for (int jj = 0; jj < 8; ++jj) {
        float h = bf2f((u16)(wds[jj >> 1] >> ((jj & 1) * 16)));
        d1 += h * a_l[half * 64 + i * 8 + jj];
        d2 += h * a_l[128 + half * 64 + i * 8 + jj];
      }
    }
    d1 += __shfl_xor(d1, 1);
    d2 += __shfl_xor(d2, 1);
    if (half == 0) {
      s1p[cb * 16384 + row0 + r2] = d1;
      s2p[cb * 16384 + row0 + r2] = d2;
    }
  }
}

// ---------- prep: reduce partials; u32-key bitonic sort of s2L; E1/E2; scans ->
// exact denominators folded into c1i/c2i; kn. ----------
__global__ __launch_bounds__(1024) void k_prep(const float* __restrict__ s1p, const float* __restrict__ s2p,
                                               float* __restrict__ e1s, float* __restrict__ e2s,
                                               u32* __restrict__ permM, u32* __restrict__ kng,
                                               float* __restrict__ c1ig, float* __restrict__ c2ig) {
  __shared__ u32 sk[1024];
  __shared__ float s2all[1024];
  __shared__ float s2sv[1024];
  __shared__ float arrA[1024];
  __shared__ float arrB[1024];
  const int b = blockIdx.x;
  const int t = threadIdx.x;
  const int id = b * 1024 + t;

  const float s1v = (s1p[id] + s1p[16384 + id] + s1p[32768 + id] + s1p[49152 + id]) * LOG2E;
  const float s2v = (s2p[id] + s2p[16384 + id] + s2p[32768 + id] + s2p[49152 + id]) * LOG2E;
  s2all[t] = s2v;

  {
    u32 bits = __builtin_bit_cast(u32, s2v);
    u32 key = (bits & 0x80000000u) ? ~bits : (bits | 0x80000000u);
    sk[t] = (key & 0xFFFFFC00u) | (u32)t;   // truncated key | idx
  }
  for (int size = 2; size <= 1024; size <<= 1)
    for (int stride = size >> 1; stride > 0; stride >>= 1) {
      __syncthreads();
      int ixj = t ^ stride;
      if (ixj > t) {
        u32 va = sk[t], vb = sk[ixj];
        bool asc = ((t & size) == 0);
        if ((va > vb) == asc) { sk[t] = vb; sk[ixj] = va; }
      }
    }
  __syncthreads();

  const u32 idx = sk[t] & 1023u;
  const float sv = s2all[idx];
  s2sv[t] = sv;
  __syncthreads();

  const float E1 = exp2f(sv), E2 = exp2f(ALPHA * sv);
  e1s[b * 1024 + t] = E1;
  e2s[b * 1024 + t] = E2;
  permM[b * 1024 + t] = idx;
  arrA[t] = E2;
  arrB[t] = exp2f(s2sv[1023 - t]);
  __syncthreads();

  for (int off = 1; off < 1024; off <<= 1) {
    float aA = (t >= off) ? arrA[t - off] : 0.f;
    float aB = (t >= off) ? arrB[t - off] : 0.f;
    __syncthreads();
    arrA[t] += aA;
    arrB[t] += aB;
    __syncthreads();
  }

  {
    const float thr = -s1v;
    int lo = 0, hi = 1024;
    while (lo < hi) { int mid = (lo + hi) >> 1; if (s2sv[mid] <= thr) lo = mid + 1; else hi = mid; }
    const int kn = lo;
    float se1suf = (kn == 1024) ? 0.f : arrB[1023 - kn];
    float se2pre = (kn == 0) ? 0.f : arrA[kn - 1];
    const float c1 = exp2f(s1v), c2 = exp2f(ALPHA * s1v);
    const float inv = 1.0f / (c1 * se1suf + c2 * se2pre);
    c1ig[id] = c1 * inv;
    c2ig[id] = c2 * inv;
    kng[id] = (u32)kn;
  }
}

// ---------- sweep2: per (b, 16-f chunk), 512 threads (32 segs x 16 f).
// Per-element packed scan table Cp[i][f] = (bf16 suffix e1·h | bf16 excl-prefix e2·h).
// Phase 2: single u32 lookup per (n,f) + fused elu output. 2 blocks/CU. ----------
__global__ __launch_bounds__(512, 2) void k_sweep2(const u16* __restrict__ hbf,
                                                   const float* __restrict__ e1s, const float* __restrict__ e2s,
                                                   const u32* __restrict__ permM, const u32* __restrict__ kng,
                                                   const float* __restrict__ c1ig, const float* __restrict__ c2ig,
                                                   const float* __restrict__ betag, float* __restrict__ out) {
  __shared__ u32 Cp[1025][17];     // pad 17: row->bank shift (conflict-free walks)
  __shared__ float segS1[32][16];
  __shared__ float segP2[32][16];

  const int t = threadIdx.x;       // 0..511
  const int B = blockIdx.x;
  const int b = (B & 7) * 2 + ((B >> 3) & 1);   // XCD swizzle: batch's 32 blocks share an XCD
  const int fc = B >> 4;                         // 0..31 : 16-f chunk

  const u16* hB = hbf + (size_t)b * 1024 * 512 + fc * 16;

  // phase 1: thread (seg=t>>4, f=t&15) owns sorted positions [seg*32, seg*32+32)
  const int f = t & 15;
  const int seg = t >> 4;          // 0..31
  const int i0 = seg * 32;
  const u32* permB = permM + b * 1024 + i0;
  const float* e1B = e1s + b * 1024 + i0;
  const float* e2B = e2s + b * 1024 + i0;

  // pass A: gather 32 sorted h values (packed bf16 pairs) + per-seg totals
  u32 hpk[16];
  float ss1 = 0.f, ss2 = 0.f;
#pragma unroll
  for (int c = 0; c < 32; c += 2) {
    u16 h0 = hB[(size_t)permB[c] * 512 + f];
    u16 h1 = hB[(size_t)permB[c + 1] * 512 + f];
    hpk[c >> 1] = (u32)h0 | ((u32)h1 << 16);
    ss1 = fmaf(e1B[c], bf2f(h0), ss1);
    ss1 = fmaf(e1B[c + 1], bf2f(h1), ss1);
    ss2 = fmaf(e2B[c], bf2f(h0), ss2);
    ss2 = fmaf(e2B[c + 1], bf2f(h1), ss2);
  }
  segS1[seg][f] = ss1;
  segP2[seg][f] = ss2;
  __syncthreads();

  float sufAfter = 0.f, preBefore = 0.f;
#pragma unroll
  for (int s7 = 0; s7 < 32; ++s7) {
    if (s7 > seg) sufAfter += segS1[s7][f];
    if (s7 < seg) preBefore += segP2[s7][f];
  }

  // pass B: backward walk -> packed suffix values in 16 u32 regs
  u32 c1p[16];
  {
    float run1 = sufAfter;
#pragma unroll
    for (int c = 31; c >= 0; --c) {
      u16 hv = (u16)(hpk[c >> 1] >> ((c & 1) * 16));
      run1 = fmaf(e1B[c], bf2f(hv), run1);
      if (c & 1) c1p[c >> 1] = (u32)f2bf(run1) << 16;
      else c1p[c >> 1] |= (u32)f2bf(run1);
    }
  }
  // pass C: forward walk -> packed (suffix | excl-prefix) store
  {
    float run2 = preBefore;
#pragma unroll
    for (int c = 0; c < 32; ++c) {
      u16 c1v = (u16)(c1p[c >> 1] >> ((c & 1) * 16));
      Cp[i0 + c][f] = (u32)c1v | ((u32)f2bf(run2) << 16);
      u16 hv = (u16)(hpk[c >> 1] >> ((c & 1) * 16));
      run2 = fmaf(e2B[c], bf2f(hv), run2);
    }
    if (seg == 31) Cp[1024][f] = (u32)f2bf(run2) << 16;   // kn=1024 sentinel: A=0, B=total
  }
  __syncthreads();

  // phase 2: per row n: one packed lookup + fused elu output (32 rows/iter, 32 iters)
  const float beta = betag[0];
  const int nl = t >> 4;           // 0..31
  const u32* knB = kng + b * 1024;
  const float* c1B = c1ig + b * 1024;
  const float* c2B = c2ig + b * 1024;
#pragma unroll 4
  for (int r = 0; r < 32; ++r) {
    const int n = r * 32 + nl;
    const int kn = (int)knB[n];
    const u32 cp = Cp[kn][f];
    const float A = bf2f((u16)(cp & 0xFFFFu));
    const float Bv = bf2f((u16)(cp >> 16));
    const float hvn = bf2f(hB[(size_t)n * 512 + f]);
    const float xv = c1B[n] * A + c2B[n] * Bv + beta * hvn;
    out[((size_t)b * 1024 + n) * 512 + fc * 16 + f] = xv > 0.f ? xv : __expf(xv) - 1.0f;
  }
}

extern "C" void kernel_launch(void* const* d_in, const int* in_sizes, int n_in,
                              void* d_out, int out_size, void* d_ws, size_t ws_size,
                              hipStream_t stream) {
  const float* x = (const float*)d_in[0];
  const float* W = (const float*)d_in[1];
  const float* a = (const float*)d_in[2];
  const float* beta = (const float*)d_in[3];
  float* out = (float*)d_out;

  char* ws = (char*)d_ws;
  u16* hbf = (u16*)ws;                                   // [0, 16M)
  char* sm = ws + (16u << 20);
  float* e1s = (float*)(sm);                             // 64 KB each
  float* e2s = (float*)(sm + (64u << 10));
  u32* permM = (u32*)(sm + (128u << 10));
  u32* kng = (u32*)(sm + (192u << 10));
  float* c1i = (float*)(sm + (256u << 10));
  float* c2i = (float*)(sm + (320u << 10));
  float* s1p = (float*)(sm + (512u << 10));              // 256 KB
  float* s2p = (float*)(sm + (768u << 10));              // 256 KB
  u16* wbt = (u16*)(sm + (1024u << 10));                 // 512 KB

  k_cast_wT<<<1024, 256, 0, stream>>>(W, wbt);
  k_gemm1<<<512, 256, 0, stream>>>(x, wbt, a, hbf, s1p, s2p);
  k_prep<<<16, 1024, 0, stream>>>(s1p, s2p, e1s, e2s, permM, kng, c1i, c2i);
  k_sweep2<<<512, 512, 0, stream>>>(hbf, e1s, e2s, permM, kng, c1i, c2i, beta, out);
}

// Round 18
// 62.132 us; speedup vs baseline: 1.1679x; 1.1679x over previous
//
#include <hip/hip_runtime.h>

using u16 = unsigned short;
using u32 = unsigned int;
using u64 = unsigned long long;

#define ALPHA 0.2f
#define LOG2E 1.4426950408889634f

typedef __bf16 bf16x8 __attribute__((ext_vector_type(8)));
typedef float f32x4 __attribute__((ext_vector_type(4)));
typedef float f32x16 __attribute__((ext_vector_type(16)));

__device__ __forceinline__ u16 f2bf(float f) {
  u32 u = __builtin_bit_cast(u32, f);
  u += 0x7FFFu + ((u >> 16) & 1u);   // RTNE
  return (u16)(u >> 16);
}
__device__ __forceinline__ float bf2f(u16 h) {
  u32 u = ((u32)h) << 16;
  return __builtin_bit_cast(float, u);
}
__device__ __forceinline__ void gload_lds16(const void* g, void* l) {
  __builtin_amdgcn_global_load_lds((__attribute__((address_space(1))) void*)g,
                                   (__attribute__((address_space(3))) void*)l,
                                   16, 0, 0);
}

// ---------- cast+transpose W: wbt[n][k] = bf16(W[k][n]) ----------
__global__ __launch_bounds__(256) void k_cast_wT(const float* __restrict__ W, u16* __restrict__ wbt) {
  int idx = blockIdx.x * 256 + threadIdx.x;
  int k = idx >> 9, n = idx & 511;
  wbt[n * 512 + k] = f2bf(W[idx]);
}

// ---------- gemm1: h = x@W (M=16384,K=512,N=512). 128x128 tile, 4 waves.
// Triple-buffered, counted vmcnt, XCD-swizzled. Epilogue: hbf + score partials.
__global__ __launch_bounds__(256, 2) void k_gemm1(const float* __restrict__ x, const u16* __restrict__ wbt,
                                                  const float* __restrict__ a,
                                                  u16* __restrict__ hbf,
                                                  float* __restrict__ s1p, float* __restrict__ s2p) {
  __shared__ __attribute__((aligned(16))) char lds[73728];
  __shared__ __attribute__((aligned(16))) float a_l[256];

  const int t = threadIdx.x;
  const int lane = t & 63;
  const int w = t >> 6;
  const int l31 = lane & 31, lhi = lane >> 5;
  const int rb = w >> 1, cg = w & 1;
  const int g = blockIdx.x;
  const int cb = (g >> 3) & 3;
  const int tile_m = (g & 7) | ((g >> 5) << 3);
  const int row0 = tile_m * 128;
  const int col0 = cb * 128;

  a_l[t] = (t < 128) ? a[col0 + t] : a[512 + col0 + (t - 128)];

  f32x16 acc[2][2];
#pragma unroll
  for (int i = 0; i < 2; ++i)
#pragma unroll
    for (int j = 0; j < 2; ++j)
#pragma unroll
      for (int r = 0; r < 16; ++r) acc[i][j][r] = 0.f;

#define STAGE_G1(kt, Ab, Bb)                                                              \
  {                                                                                       \
    const int k0_ = (kt) * 32;                                                            \
    _Pragma("unroll")                                                                     \
    for (int i = 0; i < 4; ++i) {                                                         \
      int G = i * 256 + t;                                                                \
      int row = G >> 3, ks = G & 7;                                                       \
      gload_lds16(x + (size_t)(row0 + row) * 512 + k0_ + ((ks ^ (row & 7)) * 4),          \
                  (Ab) + (size_t)(i * 256 + w * 64) * 16);                                \
    }                                                                                     \
    _Pragma("unroll")                                                                     \
    for (int i = 0; i < 2; ++i) {                                                         \
      int G = i * 256 + t;                                                                \
      int col = G >> 2, ks = G & 3;                                                       \
      gload_lds16(wbt + (size_t)(col0 + col) * 512 + k0_ + ((ks ^ ((col >> 1) & 3)) * 8), \
                  (Bb) + (size_t)(i * 256 + w * 64) * 16);                                \
    }                                                                                     \
  }

#define COMPUTE_G1(Ab, Bb)                                                                         \
  {                                                                                                \
    _Pragma("unroll")                                                                              \
    for (int ks = 0; ks < 2; ++ks) {                                                               \
      bf16x8 af[2];                                                                                \
      _Pragma("unroll")                                                                            \
      for (int sub = 0; sub < 2; ++sub) {                                                          \
        const int arow = rb * 64 + sub * 32 + l31;                                                 \
        const int kg = ks * 4 + lhi * 2;                                                           \
        f32x4 fa0 = *reinterpret_cast<const f32x4*>((Ab) + (size_t)(arow * 8 + (kg ^ (arow & 7))) * 16); \
        f32x4 fa1 = *reinterpret_cast<const f32x4*>((Ab) + (size_t)(arow * 8 + ((kg + 1) ^ (arow & 7))) * 16); \
        _Pragma("unroll")                                                                          \
        for (int jj = 0; jj < 4; ++jj) {                                                           \
          af[sub][jj] = (__bf16)fa0[jj];                                                           \
          af[sub][jj + 4] = (__bf16)fa1[jj];                                                       \
        }                                                                                          \
      }                                                                                            \
      bf16x8 bfr[2];                                                                               \
      _Pragma("unroll")                                                                            \
      for (int bt = 0; bt < 2; ++bt) {                                                             \
        const int bcol = cg * 64 + bt * 32 + l31;                                                  \
        const int kslot = (ks * 2 + lhi) ^ ((bcol >> 1) & 3);                                      \
        bfr[bt] = *reinterpret_cast<const bf16x8*>((Bb) + (size_t)(bcol * 4 + kslot) * 16);        \
      }                                                                                            \
      _Pragma("unroll")                                                                            \
      for (int sub = 0; sub < 2; ++sub)                                                            \
        _Pragma("unroll")                                                                          \
        for (int bt = 0; bt < 2; ++bt)                                                             \
          acc[sub][bt] = __builtin_amdgcn_mfma_f32_32x32x16_bf16(af[sub], bfr[bt], acc[sub][bt], 0, 0, 0); \
    }                                                                                              \
  }

  char* Ac = lds;             char* Bc = lds + 49152;
  char* An = lds + 16384;     char* Bn = lds + 57344;
  char* As = lds + 32768;     char* Bs = lds + 65536;

  STAGE_G1(0, Ac, Bc);
  STAGE_G1(1, An, Bn);
  __builtin_amdgcn_sched_barrier(0);
  asm volatile("s_waitcnt vmcnt(6) lgkmcnt(0)" ::: "memory");
  __builtin_amdgcn_s_barrier();
  __builtin_amdgcn_sched_barrier(0);

#pragma unroll 1
  for (int kt = 0; kt < 14; ++kt) {
    STAGE_G1(kt + 2, As, Bs);
    COMPUTE_G1(Ac, Bc);
    __builtin_amdgcn_sched_barrier(0);
    asm volatile("s_waitcnt vmcnt(6)" ::: "memory");
    __builtin_amdgcn_s_barrier();
    __builtin_amdgcn_sched_barrier(0);
    char* ta = Ac; Ac = An; An = As; As = ta;
    char* tb = Bc; Bc = Bn; Bn = Bs; Bs = tb;
  }
  COMPUTE_G1(Ac, Bc);
  __builtin_amdgcn_sched_barrier(0);
  asm volatile("s_waitcnt vmcnt(0)" ::: "memory");
  __builtin_amdgcn_s_barrier();
  __builtin_amdgcn_sched_barrier(0);
  COMPUTE_G1(An, Bn);
#undef STAGE_G1
#undef COMPUTE_G1

  __syncthreads();

  u16* lT = (u16*)lds;
#pragma unroll
  for (int sub = 0; sub < 2; ++sub)
#pragma unroll
    for (int bt = 0; bt < 2; ++bt) {
      const int col = cg * 64 + bt * 32 + l31;
#pragma unroll
      for (int r = 0; r < 16; ++r) {
        int row = rb * 64 + sub * 32 + (r & 3) + 8 * (r >> 2) + 4 * lhi;
        lT[row * 136 + col] = f2bf(acc[sub][bt][r]);
      }
    }
  __syncthreads();

#pragma unroll
  for (int i = 0; i < 8; ++i) {
    int G = i * 256 + t;
    int row = G >> 4, gg = G & 15;
    uint4 v = *reinterpret_cast<const uint4*>(&lT[row * 136 + gg * 8]);
    *reinterpret_cast<uint4*>(&hbf[(size_t)(row0 + row) * 512 + col0 + gg * 8]) = v;
  }
  {
    const int r2 = t >> 1, half = t & 1;
    float d1 = 0.f, d2 = 0.f;
#pragma unroll
    for (int i = 0; i < 8; ++i) {
      uint4 v = *reinterpret_cast<const uint4*>(&lT[r2 * 136 + half * 64 + i * 8]);
      u32 wds[4] = {v.x, v.y, v.z, v.w};
#pragma unroll
      for (int jj = 0; jj < 8; ++jj) {
        float h = bf2f((u16)(wds[jj >> 1] >> ((jj & 1) * 16)));
        d1 += h * a_l[half * 64 + i * 8 + jj];
        d2 += h * a_l[128 + half * 64 + i * 8 + jj];
      }
    }
    d1 += __shfl_xor(d1, 1);
    d2 += __shfl_xor(d2, 1);
    if (half == 0) {
      s1p[cb * 16384 + row0 + r2] = d1;
      s2p[cb * 16384 + row0 + r2] = d2;
    }
  }
}

// ---------- prep: reduce partials; hybrid shfl/LDS bitonic sort (14 barriers);
// wave-shfl scans (2 barriers); exact denominators folded into c1i/c2i; kn. ----------
__global__ __launch_bounds__(1024) void k_prep(const float* __restrict__ s1p, const float* __restrict__ s2p,
                                               float* __restrict__ e1s, float* __restrict__ e2s,
                                               u32* __restrict__ permM, u32* __restrict__ kng,
                                               float* __restrict__ c1ig, float* __restrict__ c2ig) {
  __shared__ u32 sk[1024];
  __shared__ float s2all[1024];
  __shared__ float s2sv[1024];
  __shared__ float arrA[1024];
  __shared__ float arrB[1024];
  __shared__ float wtA[16], wtB[16];
  const int b = blockIdx.x;
  const int t = threadIdx.x;
  const int lane = t & 63, wid = t >> 6;
  const int id = b * 1024 + t;

  const float s1v = (s1p[id] + s1p[16384 + id] + s1p[32768 + id] + s1p[49152 + id]) * LOG2E;
  const float s2v = (s2p[id] + s2p[16384 + id] + s2p[32768 + id] + s2p[49152 + id]) * LOG2E;
  s2all[t] = s2v;

  u32 key;
  {
    u32 bits = __builtin_bit_cast(u32, s2v);
    u32 k2 = (bits & 0x80000000u) ? ~bits : (bits | 0x80000000u);
    key = (k2 & 0xFFFFFC00u) | (u32)t;   // truncated key | idx
  }

#define SHFL_CE(size_, stride_)                                            \
  {                                                                        \
    u32 partner = (u32)__shfl_xor((int)key, (stride_));                    \
    bool dir = ((t & (size_)) == 0);                                       \
    bool keepMin = (dir == ((t & (stride_)) == 0));                        \
    key = keepMin ? (key < partner ? key : partner)                        \
                  : (key > partner ? key : partner);                       \
  }

  // sizes 2..64: fully intra-wave, zero barriers
#pragma unroll
  for (int size = 2; size <= 64; size <<= 1)
#pragma unroll
    for (int stride = size >> 1; stride > 0; stride >>= 1) SHFL_CE(size, stride);

  // sizes 128..1024: LDS for strides>=64, shfl for strides<=32
#pragma unroll 1
  for (int size = 128; size <= 1024; size <<= 1) {
    sk[t] = key;
#pragma unroll 1
    for (int stride = size >> 1; stride >= 64; stride >>= 1) {
      __syncthreads();
      int ixj = t ^ stride;
      if (ixj > t) {
        u32 va = sk[t], vb = sk[ixj];
        bool asc = ((t & size) == 0);
        if ((va > vb) == asc) { sk[t] = vb; sk[ixj] = va; }
      }
    }
    __syncthreads();
    key = sk[t];
#pragma unroll
    for (int stride = 32; stride > 0; stride >>= 1) SHFL_CE(size, stride);
  }
#undef SHFL_CE

  const u32 idx = key & 1023u;
  const float sv = s2all[idx];
  s2sv[t] = sv;
  __syncthreads();

  const float E1 = exp2f(sv), E2 = exp2f(ALPHA * sv);
  e1s[b * 1024 + t] = E1;
  e2s[b * 1024 + t] = E2;
  permM[b * 1024 + t] = idx;

  // inclusive scans: aA = prefix of E2 (sorted order), aB = prefix of reversed E1
  float aA = E2;
  float aB = exp2f(s2sv[1023 - t]);
#pragma unroll
  for (int off = 1; off < 64; off <<= 1) {
    float uA = __shfl_up(aA, off);
    float uB = __shfl_up(aB, off);
    if (lane >= off) { aA += uA; aB += uB; }
  }
  if (lane == 63) { wtA[wid] = aA; wtB[wid] = aB; }
  __syncthreads();
  {
    float offA = 0.f, offB = 0.f;
#pragma unroll
    for (int i2 = 0; i2 < 16; ++i2) {
      float vA2 = wtA[i2], vB2 = wtB[i2];
      if (i2 < wid) { offA += vA2; offB += vB2; }
    }
    aA += offA;
    aB += offB;
  }
  arrA[t] = aA;
  arrB[t] = aB;
  __syncthreads();

  {
    const float thr = -s1v;
    int lo = 0, hi = 1024;
    while (lo < hi) { int mid = (lo + hi) >> 1; if (s2sv[mid] <= thr) lo = mid + 1; else hi = mid; }
    const int kn = lo;
    float se1suf = (kn == 1024) ? 0.f : arrB[1023 - kn];
    float se2pre = (kn == 0) ? 0.f : arrA[kn - 1];
    const float c1 = exp2f(s1v), c2 = exp2f(ALPHA * s1v);
    const float inv = 1.0f / (c1 * se1suf + c2 * se2pre);
    c1ig[id] = c1 * inv;
    c2ig[id] = c2 * inv;
    kng[id] = (u32)kn;
  }
}

// ---------- sweep2 (r16 structure, 256 thr): per (b, 16-f chunk), per-element
// PACKED scan table Cp[phys(i)][f] = (bf16 suffix e1·h | bf16 excl-prefix e2·h),
// phys(i)=i+(i>>6) pad breaks seg-group bank alignment. Phase 2: one lookup. ----------
__global__ __launch_bounds__(256, 2) void k_sweep2(const u16* __restrict__ hbf,
                                                   const float* __restrict__ e1s, const float* __restrict__ e2s,
                                                   const u32* __restrict__ permM, const u32* __restrict__ kng,
                                                   const float* __restrict__ c1ig, const float* __restrict__ c2ig,
                                                   const float* __restrict__ betag, float* __restrict__ out) {
  __shared__ u32 Cp[1041][16];     // phys rows: 1024 + 16 pads + sentinel
  __shared__ float c1i_l[1024];
  __shared__ float c2i_l[1024];
  __shared__ u16 kn_l[1024];
  __shared__ float segS1[16][16];
  __shared__ float segP2[16][16];

  const int t = threadIdx.x;
  const int B = blockIdx.x;
  const int b = (B & 7) * 2 + ((B >> 3) & 1);   // XCD swizzle: batch's 32 blocks share an XCD
  const int fc = B >> 4;                         // 0..31 : 16-f chunk

  const u16* hB = hbf + (size_t)b * 1024 * 512 + fc * 16;

#pragma unroll
  for (int q = 0; q < 4; ++q) {
    int i = q * 256 + t;
    c1i_l[i] = c1ig[b * 1024 + i];
    c2i_l[i] = c2ig[b * 1024 + i];
    kn_l[i] = (u16)kng[b * 1024 + i];
  }

  // phase 1: thread (seg=t>>4, f=t&15) owns sorted positions [seg*64, seg*64+64)
  const int f = t & 15;
  const int seg = t >> 4;
  const int i0 = seg * 64;
  const int p0 = i0 + seg;         // phys base: i + (i>>6)
  const u32* permB = permM + b * 1024 + i0;
  const float* e1B = e1s + b * 1024 + i0;
  const float* e2B = e2s + b * 1024 + i0;

  // pass A: gather h (packed bf16 pairs in 32 regs) + per-seg totals
  u32 hpk[32];
  float ss1 = 0.f, ss2 = 0.f;
#pragma unroll 8
  for (int c = 0; c < 64; c += 2) {
    u16 h0 = hB[(size_t)permB[c] * 512 + f];
    u16 h1 = hB[(size_t)permB[c + 1] * 512 + f];
    hpk[c >> 1] = (u32)h0 | ((u32)h1 << 16);
    ss1 = fmaf(e1B[c], bf2f(h0), ss1);
    ss1 = fmaf(e1B[c + 1], bf2f(h1), ss1);
    ss2 = fmaf(e2B[c], bf2f(h0), ss2);
    ss2 = fmaf(e2B[c + 1], bf2f(h1), ss2);
  }
  segS1[seg][f] = ss1;
  segP2[seg][f] = ss2;
  __syncthreads();

  float sufAfter = 0.f, preBefore = 0.f;
#pragma unroll
  for (int s7 = 0; s7 < 16; ++s7) {
    if (s7 > seg) sufAfter += segS1[s7][f];
    if (s7 < seg) preBefore += segP2[s7][f];
  }

  // pass B: backward walk -> packed bf16 suffix values in 32 regs
  u32 c1p[32];
  {
    float run1 = sufAfter;
#pragma unroll
    for (int c = 63; c >= 0; --c) {
      u16 hv = (u16)(hpk[c >> 1] >> ((c & 1) * 16));
      run1 = fmaf(e1B[c], bf2f(hv), run1);
      if (c & 1) c1p[c >> 1] = (u32)f2bf(run1) << 16;
      else c1p[c >> 1] |= (u32)f2bf(run1);
    }
  }
  // pass C: forward walk -> packed (suffix | excl-prefix) store
  {
    float run2 = preBefore;
#pragma unroll
    for (int c = 0; c < 64; ++c) {
      u16 c1v = (u16)(c1p[c >> 1] >> ((c & 1) * 16));
      Cp[p0 + c][f] = (u32)c1v | ((u32)f2bf(run2) << 16);
      u16 hv = (u16)(hpk[c >> 1] >> ((c & 1) * 16));
      run2 = fmaf(e2B[c], bf2f(hv), run2);
    }
    if (seg == 15) Cp[1040][f] = (u32)f2bf(run2) << 16;   // kn=1024 sentinel (phys 1040)
  }
  __syncthreads();

  // phase 2: per row n: one packed lookup + fused elu output (16 rows/iter, 64 iters)
  const float beta = betag[0];
  const int nl = t >> 4;
#pragma unroll 4
  for (int r = 0; r < 64; ++r) {
    const int n = r * 16 + nl;
    const int kn = kn_l[n];
    const u32 cp = Cp[kn + (kn >> 6)][f];
    const float A = bf2f((u16)(cp & 0xFFFFu));
    const float Bv = bf2f((u16)(cp >> 16));
    const float hvn = bf2f(hB[(size_t)n * 512 + f]);
    const float xv = c1i_l[n] * A + c2i_l[n] * Bv + beta * hvn;
    out[((size_t)b * 1024 + n) * 512 + fc * 16 + f] = xv > 0.f ? xv : __expf(xv) - 1.0f;
  }
}

extern "C" void kernel_launch(void* const* d_in, const int* in_sizes, int n_in,
                              void* d_out, int out_size, void* d_ws, size_t ws_size,
                              hipStream_t stream) {
  const float* x = (const float*)d_in[0];
  const float* W = (const float*)d_in[1];
  const float* a = (const float*)d_in[2];
  const float* beta = (const float*)d_in[3];
  float* out = (float*)d_out;

  char* ws = (char*)d_ws;
  u16* hbf = (u16*)ws;                                   // [0, 16M)
  char* sm = ws + (16u << 20);
  float* e1s = (float*)(sm);                             // 64 KB each
  float* e2s = (float*)(sm + (64u << 10));
  u32* permM = (u32*)(sm + (128u << 10));
  u32* kng = (u32*)(sm + (192u << 10));
  float* c1i = (float*)(sm + (256u << 10));
  float* c2i = (float*)(sm + (320u << 10));
  float* s1p = (float*)(sm + (512u << 10));              // 256 KB
  float* s2p = (float*)(sm + (768u << 10));              // 256 KB
  u16* wbt = (u16*)(sm + (1024u << 10));                 // 512 KB

  k_cast_wT<<<1024, 256, 0, stream>>>(W, wbt);
  k_gemm1<<<512, 256, 0, stream>>>(x, wbt, a, hbf, s1p, s2p);
  k_prep<<<16, 1024, 0, stream>>>(s1p, s2p, e1s, e2s, permM, kng, c1i, c2i);
  k_sweep2<<<512, 256, 0, stream>>>(hbf, e1s, e2s, permM, kng, c1i, c2i, beta, out);
}

// Round 19
// 59.877 us; speedup vs baseline: 1.2119x; 1.0376x over previous
//
#include <hip/hip_runtime.h>

using u16 = unsigned short;
using u32 = unsigned int;
using u64 = unsigned long long;

#define ALPHA 0.2f
#define LOG2E 1.4426950408889634f

typedef __bf16 bf16x8 __attribute__((ext_vector_type(8)));
typedef float f32x4 __attribute__((ext_vector_type(4)));
typedef float f32x16 __attribute__((ext_vector_type(16)));

__device__ __forceinline__ u16 f2bf(float f) {
  u32 u = __builtin_bit_cast(u32, f);
  u += 0x7FFFu + ((u >> 16) & 1u);   // RTNE
  return (u16)(u >> 16);
}
__device__ __forceinline__ float bf2f(u16 h) {
  u32 u = ((u32)h) << 16;
  return __builtin_bit_cast(float, u);
}
__device__ __forceinline__ void gload_lds16(const void* g, void* l) {
  __builtin_amdgcn_global_load_lds((__attribute__((address_space(1))) void*)g,
                                   (__attribute__((address_space(3))) void*)l,
                                   16, 0, 0);
}

// ---------- cast+transpose W: wbt[n][k] = bf16(W[k][n]) ----------
__global__ __launch_bounds__(256) void k_cast_wT(const float* __restrict__ W, u16* __restrict__ wbt) {
  int idx = blockIdx.x * 256 + threadIdx.x;
  int k = idx >> 9, n = idx & 511;
  wbt[n * 512 + k] = f2bf(W[idx]);
}

// ---------- gemm1: h = x@W (M=16384,K=512,N=512). 128x128 tile, 4 waves.
// Triple-buffered, counted vmcnt, XCD-swizzled. Epilogue: hbf + score partials.
__global__ __launch_bounds__(256, 2) void k_gemm1(const float* __restrict__ x, const u16* __restrict__ wbt,
                                                  const float* __restrict__ a,
                                                  u16* __restrict__ hbf,
                                                  float* __restrict__ s1p, float* __restrict__ s2p) {
  __shared__ __attribute__((aligned(16))) char lds[73728];
  __shared__ __attribute__((aligned(16))) float a_l[256];

  const int t = threadIdx.x;
  const int lane = t & 63;
  const int w = t >> 6;
  const int l31 = lane & 31, lhi = lane >> 5;
  const int rb = w >> 1, cg = w & 1;
  const int g = blockIdx.x;
  const int cb = (g >> 3) & 3;
  const int tile_m = (g & 7) | ((g >> 5) << 3);
  const int row0 = tile_m * 128;
  const int col0 = cb * 128;

  a_l[t] = (t < 128) ? a[col0 + t] : a[512 + col0 + (t - 128)];

  f32x16 acc[2][2];
#pragma unroll
  for (int i = 0; i < 2; ++i)
#pragma unroll
    for (int j = 0; j < 2; ++j)
#pragma unroll
      for (int r = 0; r < 16; ++r) acc[i][j][r] = 0.f;

#define STAGE_G1(kt, Ab, Bb)                                                              \
  {                                                                                       \
    const int k0_ = (kt) * 32;                                                            \
    _Pragma("unroll")                                                                     \
    for (int i = 0; i < 4; ++i) {                                                         \
      int G = i * 256 + t;                                                                \
      int row = G >> 3, ks = G & 7;                                                       \
      gload_lds16(x + (size_t)(row0 + row) * 512 + k0_ + ((ks ^ (row & 7)) * 4),          \
                  (Ab) + (size_t)(i * 256 + w * 64) * 16);                                \
    }                                                                                     \
    _Pragma("unroll")                                                                     \
    for (int i = 0; i < 2; ++i) {                                                         \
      int G = i * 256 + t;                                                                \
      int col = G >> 2, ks = G & 3;                                                       \
      gload_lds16(wbt + (size_t)(col0 + col) * 512 + k0_ + ((ks ^ ((col >> 1) & 3)) * 8), \
                  (Bb) + (size_t)(i * 256 + w * 64) * 16);                                \
    }                                                                                     \
  }

#define COMPUTE_G1(Ab, Bb)                                                                         \
  {                                                                                                \
    _Pragma("unroll")                                                                              \
    for (int ks = 0; ks < 2; ++ks) {                                                               \
      bf16x8 af[2];                                                                                \
      _Pragma("unroll")                                                                            \
      for (int sub = 0; sub < 2; ++sub) {                                                          \
        const int arow = rb * 64 + sub * 32 + l31;                                                 \
        const int kg = ks * 4 + lhi * 2;                                                           \
        f32x4 fa0 = *reinterpret_cast<const f32x4*>((Ab) + (size_t)(arow * 8 + (kg ^ (arow & 7))) * 16); \
        f32x4 fa1 = *reinterpret_cast<const f32x4*>((Ab) + (size_t)(arow * 8 + ((kg + 1) ^ (arow & 7))) * 16); \
        _Pragma("unroll")                                                                          \
        for (int jj = 0; jj < 4; ++jj) {                                                           \
          af[sub][jj] = (__bf16)fa0[jj];                                                           \
          af[sub][jj + 4] = (__bf16)fa1[jj];                                                       \
        }                                                                                          \
      }                                                                                            \
      bf16x8 bfr[2];                                                                               \
      _Pragma("unroll")                                                                            \
      for (int bt = 0; bt < 2; ++bt) {                                                             \
        const int bcol = cg * 64 + bt * 32 + l31;                                                  \
        const int kslot = (ks * 2 + lhi) ^ ((bcol >> 1) & 3);                                      \
        bfr[bt] = *reinterpret_cast<const bf16x8*>((Bb) + (size_t)(bcol * 4 + kslot) * 16);        \
      }                                                                                            \
      _Pragma("unroll")                                                                            \
      for (int sub = 0; sub < 2; ++sub)                                                            \
        _Pragma("unroll")                                                                          \
        for (int bt = 0; bt < 2; ++bt)                                                             \
          acc[sub][bt] = __builtin_amdgcn_mfma_f32_32x32x16_bf16(af[sub], bfr[bt], acc[sub][bt], 0, 0, 0); \
    }                                                                                              \
  }

  char* Ac = lds;             char* Bc = lds + 49152;
  char* An = lds + 16384;     char* Bn = lds + 57344;
  char* As = lds + 32768;     char* Bs = lds + 65536;

  STAGE_G1(0, Ac, Bc);
  STAGE_G1(1, An, Bn);
  __builtin_amdgcn_sched_barrier(0);
  asm volatile("s_waitcnt vmcnt(6) lgkmcnt(0)" ::: "memory");
  __builtin_amdgcn_s_barrier();
  __builtin_amdgcn_sched_barrier(0);

#pragma unroll 1
  for (int kt = 0; kt < 14; ++kt) {
    STAGE_G1(kt + 2, As, Bs);
    COMPUTE_G1(Ac, Bc);
    __builtin_amdgcn_sched_barrier(0);
    asm volatile("s_waitcnt vmcnt(6)" ::: "memory");
    __builtin_amdgcn_s_barrier();
    __builtin_amdgcn_sched_barrier(0);
    char* ta = Ac; Ac = An; An = As; As = ta;
    char* tb = Bc; Bc = Bn; Bn = Bs; Bs = tb;
  }
  COMPUTE_G1(Ac, Bc);
  __builtin_amdgcn_sched_barrier(0);
  asm volatile("s_waitcnt vmcnt(0)" ::: "memory");
  __builtin_amdgcn_s_barrier();
  __builtin_amdgcn_sched_barrier(0);
  COMPUTE_G1(An, Bn);
#undef STAGE_G1
#undef COMPUTE_G1

  __syncthreads();

  u16* lT = (u16*)lds;
#pragma unroll
  for (int sub = 0; sub < 2; ++sub)
#pragma unroll
    for (int bt = 0; bt < 2; ++bt) {
      const int col = cg * 64 + bt * 32 + l31;
#pragma unroll
      for (int r = 0; r < 16; ++r) {
        int row = rb * 64 + sub * 32 + (r & 3) + 8 * (r >> 2) + 4 * lhi;
        lT[row * 136 + col] = f2bf(acc[sub][bt][r]);
      }
    }
  __syncthreads();

#pragma unroll
  for (int i = 0; i < 8; ++i) {
    int G = i * 256 + t;
    int row = G >> 4, gg = G & 15;
    uint4 v = *reinterpret_cast<const uint4*>(&lT[row * 136 + gg * 8]);
    *reinterpret_cast<uint4*>(&hbf[(size_t)(row0 + row) * 512 + col0 + gg * 8]) = v;
  }
  {
    const int r2 = t >> 1, half = t & 1;
    float d1 = 0.f, d2 = 0.f;
#pragma unroll
    for (int i = 0; i < 8; ++i) {
      uint4 v = *reinterpret_cast<const uint4*>(&lT[r2 * 136 + half * 64 + i * 8]);
      u32 wds[4] = {v.x, v.y, v.z, v.w};
#pragma unroll
      for (int jj = 0; jj < 8; ++jj) {
        float h = bf2f((u16)(wds[jj >> 1] >> ((jj & 1) * 16)));
        d1 += h * a_l[half * 64 + i * 8 + jj];
        d2 += h * a_l[128 + half * 64 + i * 8 + jj];
      }
    }
    d1 += __shfl_xor(d1, 1);
    d2 += __shfl_xor(d2, 1);
    if (half == 0) {
      s1p[cb * 16384 + row0 + r2] = d1;
      s2p[cb * 16384 + row0 + r2] = d2;
    }
  }
}

// ---------- prep: reduce partials; hybrid shfl/LDS bitonic sort (14 barriers);
// wave-shfl scans (2 barriers); exact denominators folded into c1i/c2i; kn. ----------
__global__ __launch_bounds__(1024) void k_prep(const float* __restrict__ s1p, const float* __restrict__ s2p,
                                               float* __restrict__ e1s, float* __restrict__ e2s,
                                               u32* __restrict__ permM, u32* __restrict__ kng,
                                               float* __restrict__ c1ig, float* __restrict__ c2ig) {
  __shared__ u32 sk[1024];
  __shared__ float s2all[1024];
  __shared__ float s2sv[1024];
  __shared__ float arrA[1024];
  __shared__ float arrB[1024];
  __shared__ float wtA[16], wtB[16];
  const int b = blockIdx.x;
  const int t = threadIdx.x;
  const int lane = t & 63, wid = t >> 6;
  const int id = b * 1024 + t;

  const float s1v = (s1p[id] + s1p[16384 + id] + s1p[32768 + id] + s1p[49152 + id]) * LOG2E;
  const float s2v = (s2p[id] + s2p[16384 + id] + s2p[32768 + id] + s2p[49152 + id]) * LOG2E;
  s2all[t] = s2v;

  u32 key;
  {
    u32 bits = __builtin_bit_cast(u32, s2v);
    u32 k2 = (bits & 0x80000000u) ? ~bits : (bits | 0x80000000u);
    key = (k2 & 0xFFFFFC00u) | (u32)t;   // truncated key | idx
  }

#define SHFL_CE(size_, stride_)                                            \
  {                                                                        \
    u32 partner = (u32)__shfl_xor((int)key, (stride_));                    \
    bool dir = ((t & (size_)) == 0);                                       \
    bool keepMin = (dir == ((t & (stride_)) == 0));                        \
    key = keepMin ? (key < partner ? key : partner)                        \
                  : (key > partner ? key : partner);                       \
  }

#pragma unroll
  for (int size = 2; size <= 64; size <<= 1)
#pragma unroll
    for (int stride = size >> 1; stride > 0; stride >>= 1) SHFL_CE(size, stride);

#pragma unroll 1
  for (int size = 128; size <= 1024; size <<= 1) {
    sk[t] = key;
#pragma unroll 1
    for (int stride = size >> 1; stride >= 64; stride >>= 1) {
      __syncthreads();
      int ixj = t ^ stride;
      if (ixj > t) {
        u32 va = sk[t], vb = sk[ixj];
        bool asc = ((t & size) == 0);
        if ((va > vb) == asc) { sk[t] = vb; sk[ixj] = va; }
      }
    }
    __syncthreads();
    key = sk[t];
#pragma unroll
    for (int stride = 32; stride > 0; stride >>= 1) SHFL_CE(size, stride);
  }
#undef SHFL_CE

  const u32 idx = key & 1023u;
  const float sv = s2all[idx];
  s2sv[t] = sv;
  __syncthreads();

  const float E1 = exp2f(sv), E2 = exp2f(ALPHA * sv);
  e1s[b * 1024 + t] = E1;
  e2s[b * 1024 + t] = E2;
  permM[b * 1024 + t] = idx;

  float aA = E2;
  float aB = exp2f(s2sv[1023 - t]);
#pragma unroll
  for (int off = 1; off < 64; off <<= 1) {
    float uA = __shfl_up(aA, off);
    float uB = __shfl_up(aB, off);
    if (lane >= off) { aA += uA; aB += uB; }
  }
  if (lane == 63) { wtA[wid] = aA; wtB[wid] = aB; }
  __syncthreads();
  {
    float offA = 0.f, offB = 0.f;
#pragma unroll
    for (int i2 = 0; i2 < 16; ++i2) {
      float vA2 = wtA[i2], vB2 = wtB[i2];
      if (i2 < wid) { offA += vA2; offB += vB2; }
    }
    aA += offA;
    aB += offB;
  }
  arrA[t] = aA;
  arrB[t] = aB;
  __syncthreads();

  {
    const float thr = -s1v;
    int lo = 0, hi = 1024;
    while (lo < hi) { int mid = (lo + hi) >> 1; if (s2sv[mid] <= thr) lo = mid + 1; else hi = mid; }
    const int kn = lo;
    float se1suf = (kn == 1024) ? 0.f : arrB[1023 - kn];
    float se2pre = (kn == 0) ? 0.f : arrA[kn - 1];
    const float c1 = exp2f(s1v), c2 = exp2f(ALPHA * s1v);
    const float inv = 1.0f / (c1 * se1suf + c2 * se2pre);
    c1ig[id] = c1 * inv;
    c2ig[id] = c2 * inv;
    kng[id] = (u32)kn;
  }
}

// ---------- sweep2: per (b, 8-f chunk), 256 thr = 32 segs x 8 f. Per-element
// packed scan table Cp[phys(i)][8], phys(i)=i+(i>>5). LDS ~36KB -> 4 blocks/CU.
// Phase 2 reads kn/c1i/c2i from global (broadcast). ----------
__global__ __launch_bounds__(256, 4) void k_sweep2(const u16* __restrict__ hbf,
                                                   const float* __restrict__ e1s, const float* __restrict__ e2s,
                                                   const u32* __restrict__ permM, const u32* __restrict__ kng,
                                                   const float* __restrict__ c1ig, const float* __restrict__ c2ig,
                                                   const float* __restrict__ betag, float* __restrict__ out) {
  __shared__ u32 Cp[1060][8];      // phys rows: 1024 + 32 pads + sentinel(1056)
  __shared__ float segS1[32][8];
  __shared__ float segP2[32][8];

  const int t = threadIdx.x;
  const int B = blockIdx.x;
  const int b = (B & 7) * 2 + ((B >> 3) & 1);   // XCD swizzle: batch's 64 blocks share an XCD
  const int fc = B >> 4;                         // 0..63 : 8-f chunk

  const u16* hB = hbf + (size_t)b * 1024 * 512 + fc * 8;

  // phase 1: thread (seg=t>>3, f=t&7) owns sorted positions [seg*32, seg*32+32)
  const int f = t & 7;
  const int seg = t >> 3;          // 0..31
  const int i0 = seg * 32;
  const int p0 = seg * 33;         // phys base: i + (i>>5)
  const u32* permB = permM + b * 1024 + i0;
  const float* e1B = e1s + b * 1024 + i0;
  const float* e2B = e2s + b * 1024 + i0;

  // pass A: gather 32 sorted h values (packed pairs) + per-seg totals
  u32 hpk[16];
  float ss1 = 0.f, ss2 = 0.f;
#pragma unroll
  for (int c = 0; c < 32; c += 2) {
    u16 h0 = hB[(size_t)permB[c] * 512 + f];
    u16 h1 = hB[(size_t)permB[c + 1] * 512 + f];
    hpk[c >> 1] = (u32)h0 | ((u32)h1 << 16);
    ss1 = fmaf(e1B[c], bf2f(h0), ss1);
    ss1 = fmaf(e1B[c + 1], bf2f(h1), ss1);
    ss2 = fmaf(e2B[c], bf2f(h0), ss2);
    ss2 = fmaf(e2B[c + 1], bf2f(h1), ss2);
  }
  segS1[seg][f] = ss1;
  segP2[seg][f] = ss2;
  __syncthreads();

  float sufAfter = 0.f, preBefore = 0.f;
#pragma unroll
  for (int s7 = 0; s7 < 32; ++s7) {
    if (s7 > seg) sufAfter += segS1[s7][f];
    if (s7 < seg) preBefore += segP2[s7][f];
  }

  // pass B: backward walk -> packed bf16 suffix values in 16 regs
  u32 c1p[16];
  {
    float run1 = sufAfter;
#pragma unroll
    for (int c = 31; c >= 0; --c) {
      u16 hv = (u16)(hpk[c >> 1] >> ((c & 1) * 16));
      run1 = fmaf(e1B[c], bf2f(hv), run1);
      if (c & 1) c1p[c >> 1] = (u32)f2bf(run1) << 16;
      else c1p[c >> 1] |= (u32)f2bf(run1);
    }
  }
  // pass C: forward walk -> packed (suffix | excl-prefix) store
  {
    float run2 = preBefore;
#pragma unroll
    for (int c = 0; c < 32; ++c) {
      u16 c1v = (u16)(c1p[c >> 1] >> ((c & 1) * 16));
      Cp[p0 + c][f] = (u32)c1v | ((u32)f2bf(run2) << 16);
      u16 hv = (u16)(hpk[c >> 1] >> ((c & 1) * 16));
      run2 = fmaf(e2B[c], bf2f(hv), run2);
    }
    if (seg == 31) Cp[1056][f] = (u32)f2bf(run2) << 16;   // kn=1024 sentinel (phys 1056)
  }
  __syncthreads();

  // phase 2: per row n: one packed lookup + fused elu output (32 rows/iter, 32 iters)
  const float beta = betag[0];
  const int nl = t >> 3;           // 0..31
  const u32* knB = kng + b * 1024;
  const float* c1B = c1ig + b * 1024;
  const float* c2B = c2ig + b * 1024;
#pragma unroll 4
  for (int r = 0; r < 32; ++r) {
    const int n = r * 32 + nl;
    const int kn = (int)knB[n];
    const u32 cp = Cp[kn + (kn >> 5)][f];
    const float A = bf2f((u16)(cp & 0xFFFFu));
    const float Bv = bf2f((u16)(cp >> 16));
    const float hvn = bf2f(hB[(size_t)n * 512 + f]);
    const float xv = c1B[n] * A + c2B[n] * Bv + beta * hvn;
    out[((size_t)b * 1024 + n) * 512 + fc * 8 + f] = xv > 0.f ? xv : __expf(xv) - 1.0f;
  }
}

extern "C" void kernel_launch(void* const* d_in, const int* in_sizes, int n_in,
                              void* d_out, int out_size, void* d_ws, size_t ws_size,
                              hipStream_t stream) {
  const float* x = (const float*)d_in[0];
  const float* W = (const float*)d_in[1];
  const float* a = (const float*)d_in[2];
  const float* beta = (const float*)d_in[3];
  float* out = (float*)d_out;

  char* ws = (char*)d_ws;
  u16* hbf = (u16*)ws;                                   // [0, 16M)
  char* sm = ws + (16u << 20);
  float* e1s = (float*)(sm);                             // 64 KB each
  float* e2s = (float*)(sm + (64u << 10));
  u32* permM = (u32*)(sm + (128u << 10));
  u32* kng = (u32*)(sm + (192u << 10));
  float* c1i = (float*)(sm + (256u << 10));
  float* c2i = (float*)(sm + (320u << 10));
  float* s1p = (float*)(sm + (512u << 10));              // 256 KB
  float* s2p = (float*)(sm + (768u << 10));              // 256 KB
  u16* wbt = (u16*)(sm + (1024u << 10));                 // 512 KB

  k_cast_wT<<<1024, 256, 0, stream>>>(W, wbt);
  k_gemm1<<<512, 256, 0, stream>>>(x, wbt, a, hbf, s1p, s2p);
  k_prep<<<16, 1024, 0, stream>>>(s1p, s2p, e1s, e2s, permM, kng, c1i, c2i);
  k_sweep2<<<1024, 256, 0, stream>>>(hbf, e1s, e2s, permM, kng, c1i, c2i, beta, out);
}